// Round 5
// baseline (229.223 us; speedup 1.0000x reference)
//
#include <hip/hip_runtime.h>
#include <math.h>

#define N_  16
#define C_  128
#define T_  16384
#define K_  64
#define KG_ 73
#define CT  512           // t-chunk per block -> 512 blocks = 2 blocks/CU
#define NCH 32            // chunks per n
#define EPSN 1e-12f
#define P1  72            // xb pitch (bf16): 144B rows, 16B-aligned
#define P2  72            // st pitch (bf16)

typedef __bf16 bf16x4v __attribute__((ext_vector_type(4)));
typedef __bf16 bf16x8v __attribute__((ext_vector_type(8)));
typedef float  f32x4v  __attribute__((ext_vector_type(4)));

#define MFMA(a, b, c) __builtin_amdgcn_mfma_f32_16x16x32_bf16((a), (b), (c), 0, 0, 0)

// ---------------------------------------------------------------------------
// Kernel 1: x read ONCE as per-thread A-fragments (pipelined 1 tile ahead in
// regs) -> GEMM1 from regs -> softmax(regs) -> scatter x to LDS (swizzled)
// -> GEMM2 from LDS -> per-chunk partials (no atomics).
//   xb[c][t'] with t-chunk swizzle: t' = (t&7) + 8*((t>>3) ^ ((c>>3)&3))
//   write side: thread's 32 scatter b16s land 2-way max; read side: b128,
//   16B-aligned since (q+4)^g == (q^g)+4.
// ---------------------------------------------------------------------------
__global__ __launch_bounds__(256, 2)
void k_main(const float* __restrict__ x, const float* __restrict__ conv_w,
            float* __restrict__ gaccp, float* __restrict__ gasump)
{
    __shared__ __align__(16) __bf16 xb[2][C_ * P1];   // 2 x 18432 B
    __shared__ __align__(16) __bf16 st[2][K_ * P2];   // 2 x  9216 B
    __shared__ float asq[4 * K_];

    const int tid  = threadIdx.x;
    const int lane = tid & 63;
    const int wv   = __builtin_amdgcn_readfirstlane(tid >> 6);
    const int q    = lane >> 4;
    const int l15  = lane & 15;
    const int n     = blockIdx.x >> 5;
    const int chunk = blockIdx.x & 31;
    const int t0    = chunk * CT;

    // ---- preload W B-fragments: wf[nt][ks], cl = 16nt+l15, c = 32ks+8q+j ----
    bf16x8v wf[5][4];
#pragma unroll
    for (int nt = 0; nt < 5; ++nt) {
        const int row = min(16 * nt + l15, KG_ - 1);   // ghost rows >=73 masked later
#pragma unroll
        for (int ks = 0; ks < 4; ++ks) {
            const float* wp = conv_w + (size_t)row * C_ + 32 * ks + 8 * q;
            const float4 w0 = *(const float4*)wp;
            const float4 w1 = *(const float4*)(wp + 4);
            bf16x8v f;
            f[0] = (__bf16)w0.x; f[1] = (__bf16)w0.y; f[2] = (__bf16)w0.z; f[3] = (__bf16)w0.w;
            f[4] = (__bf16)w1.x; f[5] = (__bf16)w1.y; f[6] = (__bf16)w1.z; f[7] = (__bf16)w1.w;
            wf[nt][ks] = f;
        }
    }

    f32x4v acc2[8];
#pragma unroll
    for (int i = 0; i < 8; ++i) acc2[i] = (f32x4v){0.f, 0.f, 0.f, 0.f};
    float asum_acc[4] = {0.f, 0.f, 0.f, 0.f};

    // GEMM1 A base: element (c = 32ks+8q+j, t = t0+64it+16wv+l15)
    const float* g1 = x + ((size_t)(n * C_ + 8 * q)) * T_ + t0 + 16 * wv + l15;

    // pipelined A-frag regs (fp32), tile 0
    float pfA[32];
#pragma unroll
    for (int ks = 0; ks < 4; ++ks)
#pragma unroll
        for (int j = 0; j < 8; ++j)
            pfA[8 * ks + j] = g1[(size_t)(32 * ks + j) * T_];

    // scatter target t-position (fixed per thread): swizzle chunk by q
    const int tpos = 8 * ((2 * wv + (l15 >> 3)) ^ q) + (l15 & 7);

    int p = 0;
    for (int it = 0; it < 8; ++it) {
        // ---- convert this tile's A-frags to bf16 ----
        bf16x8v af[4];
#pragma unroll
        for (int ks = 0; ks < 4; ++ks)
#pragma unroll
            for (int j = 0; j < 8; ++j)
                af[ks][j] = (__bf16)pfA[8 * ks + j];

        // ---- scatter x tile into xb[p] (b16 writes, ~2-way via swizzle) ----
#pragma unroll
        for (int ks = 0; ks < 4; ++ks)
#pragma unroll
            for (int j = 0; j < 8; ++j)
                xb[p][(32 * ks + 8 * q + j) * P1 + tpos] = af[ks][j];

        // ---- issue next tile's A-frag loads (only outstanding VMEM) ----
        if (it < 7) {
#pragma unroll
            for (int ks = 0; ks < 4; ++ks)
#pragma unroll
                for (int j = 0; j < 8; ++j)
                    pfA[8 * ks + j] = g1[(size_t)(32 * ks + j) * T_ + (it + 1) * 64];
        }

        // ---- GEMM1 + Gram entirely from registers ----
        f32x4v acc1[5];
#pragma unroll
        for (int i = 0; i < 5; ++i) acc1[i] = (f32x4v){0.f, 0.f, 0.f, 0.f};
        f32x4v gr = (f32x4v){0.f, 0.f, 0.f, 0.f};
#pragma unroll
        for (int ks = 0; ks < 4; ++ks) {
            gr = MFMA(af[ks], af[ks], gr);
#pragma unroll
            for (int nt = 0; nt < 5; ++nt)
                acc1[nt] = MFMA(af[ks], wf[nt][ks], acc1[nt]);
        }

        // ---- rn_t from Gram diag via bpermute (t = 16wv + 4q + r) ----
        float rn[4];
#pragma unroll
        for (int r = 0; r < 4; ++r) {
            const float ss = __int_as_float(
                __builtin_amdgcn_ds_bpermute((20 * q + r) << 2, __float_as_int(gr[r])));
            rn[r] = 1.f / fmaxf(sqrtf(ss), EPSN);
        }

        // ---- softmax over 73 clusters, in registers ----
        float e[5][4];
        float d[4] = {0.f, 0.f, 0.f, 0.f};
#pragma unroll
        for (int nt = 0; nt < 5; ++nt) {
            const bool valid = (16 * nt + l15) < KG_;
#pragma unroll
            for (int r = 0; r < 4; ++r) {
                const float ev = __expf(acc1[nt][r] * rn[r]);   // |logit| <= ~13
                e[nt][r] = valid ? ev : 0.f;
                d[r] += e[nt][r];
            }
        }
#pragma unroll
        for (int r = 0; r < 4; ++r) {
            d[r] += __shfl_xor(d[r], 1);
            d[r] += __shfl_xor(d[r], 2);
            d[r] += __shfl_xor(d[r], 4);
            d[r] += __shfl_xor(d[r], 8);
            d[r] = 1.f / d[r];
        }

        // ---- soft -> st[p][cl][t] (rn folded), a_sum accumulate (fp32) ----
#pragma unroll
        for (int nt = 0; nt < 4; ++nt) {
            bf16x4v sv;
            float ap = 0.f;
#pragma unroll
            for (int r = 0; r < 4; ++r) {
                const float s = e[nt][r] * d[r];
                ap += s;
                sv[r] = (__bf16)(s * rn[r]);
            }
            asum_acc[nt] += ap;
            *(bf16x4v*)&st[p][(16 * nt + l15) * P2 + 16 * wv + 4 * q] = sv;
        }
        __syncthreads();                 // one barrier/tile: xb[p], st[p] ready

        // ---- GEMM2: wave covers 2 cl-blocks x 4 c-blocks (swizzled xf) ----
        {
            const int clp = wv >> 1;
            const int chh = wv & 1;
            bf16x8v sa[2][2];
#pragma unroll
            for (int clb = 0; clb < 2; ++clb)
#pragma unroll
                for (int ks2 = 0; ks2 < 2; ++ks2)
                    sa[clb][ks2] = *(const bf16x8v*)
                        &st[p][(16 * (2 * clp + clb) + l15) * P2 + 32 * ks2 + 8 * q];
#pragma unroll
            for (int cb = 0; cb < 4; ++cb) {
                const int nt2 = 4 * chh + cb;
                const int c = 16 * nt2 + l15;
                const int g = (2 * nt2 + (l15 >> 3)) & 3;
                const int koff = 8 * (q ^ g);
                const bf16x8v xf0 = *(const bf16x8v*)&xb[p][c * P1 + koff];
                const bf16x8v xf1 = *(const bf16x8v*)&xb[p][c * P1 + koff + 32];
                acc2[cb]     = MFMA(sa[0][0], xf0, acc2[cb]);
                acc2[cb]     = MFMA(sa[0][1], xf1, acc2[cb]);
                acc2[4 + cb] = MFMA(sa[1][0], xf0, acc2[4 + cb]);
                acc2[4 + cb] = MFMA(sa[1][1], xf1, acc2[4 + cb]);
            }
        }
        p ^= 1;
    }

    // ---- write per-chunk VLAD partials (plain stores) ----
    {
        const int clp = wv >> 1, chh = wv & 1;
        float* gp = gaccp + ((size_t)(n * NCH + chunk) * K_) * C_;
#pragma unroll
        for (int clb = 0; clb < 2; ++clb)
#pragma unroll
            for (int cb = 0; cb < 4; ++cb)
#pragma unroll
                for (int r = 0; r < 4; ++r) {
                    const int cl = 16 * (2 * clp + clb) + 4 * q + r;
                    const int c  = 16 * (4 * chh + cb) + l15;
                    gp[cl * C_ + c] = acc2[clb * 4 + cb][r];
                }
    }

    // ---- a_sum per-chunk partials ----
#pragma unroll
    for (int nt = 0; nt < 4; ++nt) {
        float v = asum_acc[nt];
        v += __shfl_xor(v, 16);
        v += __shfl_xor(v, 32);
        if (q == 0) asq[wv * K_ + 16 * nt + l15] = v;
    }
    __syncthreads();
    if (tid < K_) {
        const float s = asq[tid] + asq[K_ + tid] + asq[2 * K_ + tid] + asq[3 * K_ + tid];
        gasump[(n * NCH + chunk) * K_ + tid] = s;
    }
}

// ---------------------------------------------------------------------------
// Kernel 2a: reduce chunk partials (4 waves in parallel), centroid subtract,
// intra-norm, *cw, write out, nsq
// ---------------------------------------------------------------------------
__global__ __launch_bounds__(256)
void k_post(const float* __restrict__ gaccp, const float* __restrict__ gasump,
            const float* __restrict__ centroids, const float* __restrict__ cwv,
            float* __restrict__ out, float* __restrict__ nsq)
{
    __shared__ float red[4 * C_];
    __shared__ float ras[4];
    const int b = blockIdx.x;       // n*64 + k
    const int n = b >> 6, k = b & 63;
    const int tid = threadIdx.x, w = tid >> 6, lane = tid & 63;

    const float* gp = gaccp + ((size_t)(n * NCH) * K_ + k) * C_;
    float v0 = 0.f, v1 = 0.f;
#pragma unroll
    for (int j = 0; j < 8; ++j) {
        const size_t off = (size_t)(8 * w + j) * K_ * C_;
        v0 += gp[off + lane];
        v1 += gp[off + lane + 64];
    }
    float as = 0.f;
    const float* gs = gasump + (size_t)(n * NCH) * K_ + k;
#pragma unroll
    for (int j = 0; j < 8; ++j) as += gs[(8 * w + j) * K_];   // uniform -> s_loads

    red[w * C_ + lane]      = v0;
    red[w * C_ + 64 + lane] = v1;
    if (lane == 0) ras[w] = as;
    __syncthreads();

    if (w == 0) {
        v0 = red[lane] + red[C_ + lane] + red[2 * C_ + lane] + red[3 * C_ + lane];
        v1 = red[64 + lane] + red[C_ + 64 + lane] + red[2 * C_ + 64 + lane] + red[3 * C_ + 64 + lane];
        const float asum = ras[0] + ras[1] + ras[2] + ras[3];

        const float cv = cwv[lane];
        float cs = cv * cv;
#pragma unroll
        for (int off = 32; off; off >>= 1) cs += __shfl_xor(cs, off);
        const float cwn = cwv[k] / fmaxf(sqrtf(cs), EPSN);

        const float* ce = centroids + (size_t)k * C_;
        v0 -= asum * ce[lane];
        v1 -= asum * ce[lane + 64];
        float ss = v0 * v0 + v1 * v1;
#pragma unroll
        for (int off = 32; off; off >>= 1) ss += __shfl_xor(ss, off);
        const float scale = cwn / fmaxf(sqrtf(ss), EPSN);

        float* o = out + (size_t)n * (K_ * C_) + (size_t)k * C_;
        o[lane]      = v0 * scale;
        o[lane + 64] = v1 * scale;
        if (lane == 0) atomicAdd(&nsq[n], ss * scale * scale);
    }
}

// ---------------------------------------------------------------------------
// Kernel 2b: global L2 normalize per n
// ---------------------------------------------------------------------------
__global__ __launch_bounds__(256)
void k_norm(float* __restrict__ out, const float* __restrict__ nsq)
{
    const int i = blockIdx.x * 256 + threadIdx.x;   // 131072 total
    const int n = i >> 13;
    const float r = 1.f / fmaxf(sqrtf(nsq[n]), EPSN);
    out[i] *= r;
}

// ---------------------------------------------------------------------------
extern "C" void kernel_launch(void* const* d_in, const int* in_sizes, int n_in,
                              void* d_out, int out_size, void* d_ws, size_t ws_size,
                              hipStream_t stream)
{
    const float* x         = (const float*)d_in[0];
    const float* conv_w    = (const float*)d_in[1];
    const float* centroids = (const float*)d_in[2];
    const float* cweights  = (const float*)d_in[3];
    float* out = (float*)d_out;

    float* nsq    = (float*)d_ws;                    // [16]
    float* gasump = nsq + 16;                        // [16*32][64]
    float* gaccp  = gasump + N_ * NCH * K_;          // [16*32][64][128] = 16 MB

    hipMemsetAsync(nsq, 0, N_ * sizeof(float), stream);
    hipLaunchKernelGGL(k_main, dim3(N_ * NCH), dim3(256), 0, stream,
                       x, conv_w, gaccp, gasump);
    hipLaunchKernelGGL(k_post, dim3(N_ * K_), dim3(256), 0, stream,
                       gaccp, gasump, centroids, cweights, out, nsq);
    hipLaunchKernelGGL(k_norm, dim3(N_ * K_ * C_ / 256), dim3(256), 0, stream,
                       out, nsq);
}